// Round 1
// baseline (139.750 us; speedup 1.0000x reference)
//
#include <hip/hip_runtime.h>

// MultiHeadCrossAttention without softmax => fully linear:
//   out[b,q,h,:] = Xh[b,q,h,:] @ M[b,h]
//   M[b,h] = scale * Wq[h]^T @ Wk[h] @ (Ch^T Ch) @ Wv[h]^T
// Shapes (fixed by harness): B=2, SQ=SKV=2048, H=16, d=64, D=1024, fp32.

#define N_HEADS_ 16
#define HD_      64
#define NB_      2
#define SEQ_     2048
#define DM_      1024          // N_HEADS_*HD_
#define CHUNK_   128           // rows of context per gram block
#define NCHUNK_  (SEQ_/CHUNK_) // 16
#define NBH_     (NB_*N_HEADS_) // 32

typedef float4 f4;

__device__ __forceinline__ void ld4(float (&d)[4], const f4 v) {
  d[0]=v.x; d[1]=v.y; d[2]=v.z; d[3]=v.w;
}

// ---------------- Kernel 1: Gram matrices G[bh] = Ch^T Ch (atomic partial sums)
__global__ __launch_bounds__(256)
void gram_k(const float* __restrict__ ctx, float* __restrict__ G) {
  const int bh    = blockIdx.x & 31;
  const int chunk = blockIdx.x >> 5;
  const int b = bh >> 4, h = bh & 15;
  __shared__ f4 cT[CHUNK_][16];            // [row][col4] : 128 x 64 floats = 32 KB
  const int t = threadIdx.x;
  const f4* src = (const f4*)(ctx + ((size_t)(b*SEQ_ + chunk*CHUNK_))*DM_ + h*HD_);
  #pragma unroll
  for (int k = 0; k < (CHUNK_*16)/256; ++k) {   // 8
    int idx = t + k*256;
    cT[idx>>4][idx&15] = src[(size_t)(idx>>4)*(DM_/4) + (idx&15)];
  }
  __syncthreads();
  const int ti = t >> 4, tj = t & 15;      // e-tile, f-tile
  float acc[4][4] = {};
  #pragma unroll 4
  for (int s = 0; s < CHUNK_; ++s) {
    float ev[4], fv[4];
    ld4(ev, cT[s][ti]);
    ld4(fv, cT[s][tj]);
    #pragma unroll
    for (int i = 0; i < 4; ++i)
      #pragma unroll
      for (int j = 0; j < 4; ++j)
        acc[i][j] = fmaf(ev[i], fv[j], acc[i][j]);
  }
  float* g = G + (size_t)bh*4096;
  #pragma unroll
  for (int i = 0; i < 4; ++i)
    #pragma unroll
    for (int j = 0; j < 4; ++j)
      atomicAdd(&g[(ti*4+i)*64 + (tj*4+j)], acc[i][j]);
}

// ---------------- Kernel 2: M[b,h] = scale * Wq^T @ (Wk @ G @ Wv^T)
__device__ __forceinline__ void load_mat64(f4 (*dst)[16], const float* __restrict__ src, int t) {
  const f4* s4 = (const f4*)src;
  #pragma unroll
  for (int k = 0; k < 4; ++k) {
    int idx = t + k*256;
    dst[idx>>4][idx&15] = s4[idx];
  }
}

__global__ __launch_bounds__(256)
void combine_k(const float* __restrict__ Wq, const float* __restrict__ Wk,
               const float* __restrict__ Wv, const float* __restrict__ G,
               float* __restrict__ M) {
  const int bh = blockIdx.x;               // 0..31
  const int h  = bh & 15;
  __shared__ f4 bufA[64][16], bufB[64][16], bufC[64][16];   // 48 KB
  const int t = threadIdx.x;
  const int ti = t >> 4, tj = t & 15;

  load_mat64(bufA, Wk + (size_t)h*4096, t);      // A = Wk  [e][d1]
  load_mat64(bufB, G  + (size_t)bh*4096, t);     // B = G   [d1][d2]
  __syncthreads();

  // Phase A: T1[e][d2] = sum_d1 Wk[e][d1] * G[d1][d2]  -> bufC
  {
    float acc[4][4] = {};
    #pragma unroll 2
    for (int d14 = 0; d14 < 16; ++d14) {
      float a[4][4];
      #pragma unroll
      for (int i = 0; i < 4; ++i) ld4(a[i], bufA[ti*4+i][d14]);
      #pragma unroll
      for (int dd = 0; dd < 4; ++dd) {
        float g[4]; ld4(g, bufB[d14*4+dd][tj]);
        #pragma unroll
        for (int i = 0; i < 4; ++i)
          #pragma unroll
          for (int j = 0; j < 4; ++j)
            acc[i][j] = fmaf(a[i][dd], g[j], acc[i][j]);
      }
    }
    #pragma unroll
    for (int i = 0; i < 4; ++i)
      bufC[ti*4+i][tj] = make_float4(acc[i][0], acc[i][1], acc[i][2], acc[i][3]);
  }
  __syncthreads();
  load_mat64(bufA, Wv + (size_t)h*4096, t);      // A = Wv  [f][d2]
  __syncthreads();

  // Phase B: T2[e][f] = sum_d2 T1[e][d2] * Wv[f][d2]  -> bufB
  {
    float acc[4][4] = {};
    #pragma unroll 2
    for (int d4 = 0; d4 < 16; ++d4) {
      float a[4][4], w[4][4];
      #pragma unroll
      for (int i = 0; i < 4; ++i) ld4(a[i], bufC[ti*4+i][d4]);
      #pragma unroll
      for (int j = 0; j < 4; ++j) ld4(w[j], bufA[tj*4+j][d4]);
      #pragma unroll
      for (int i = 0; i < 4; ++i)
        #pragma unroll
        for (int j = 0; j < 4; ++j) {
          #pragma unroll
          for (int dd = 0; dd < 4; ++dd)
            acc[i][j] = fmaf(a[i][dd], w[j][dd], acc[i][j]);
        }
    }
    __syncthreads();   // everyone done reading bufC/bufA before bufB rewrite? (bufB not read in B; this sync orders the bufB write vs phase-A G reads is already past; keep for safety of bufC overwrite next)
    #pragma unroll
    for (int i = 0; i < 4; ++i)
      bufB[ti*4+i][tj] = make_float4(acc[i][0], acc[i][1], acc[i][2], acc[i][3]);
  }
  __syncthreads();
  load_mat64(bufC, Wq + (size_t)h*4096, t);      // C = Wq  [f][d]
  __syncthreads();

  // Phase C: M[d][e'] = scale * sum_f Wq[f][d] * T2[f][e']  (outer product form)
  {
    float acc[4][4] = {};
    #pragma unroll 4
    for (int f = 0; f < 64; ++f) {
      float wq[4], t2[4];
      ld4(wq, bufC[f][ti]);   // Wq[f][ti*4 .. +3]
      ld4(t2, bufB[f][tj]);   // T2[f][tj*4 .. +3]
      #pragma unroll
      for (int i = 0; i < 4; ++i)
        #pragma unroll
        for (int j = 0; j < 4; ++j)
          acc[i][j] = fmaf(wq[i], t2[j], acc[i][j]);
    }
    const float scale = 0.125f;   // 64^-0.5
    f4* m4 = (f4*)(M + (size_t)bh*4096);
    #pragma unroll
    for (int i = 0; i < 4; ++i)
      m4[(ti*4+i)*16 + tj] = make_float4(scale*acc[i][0], scale*acc[i][1],
                                         scale*acc[i][2], scale*acc[i][3]);
  }
}

// ---------------- Kernel 3: out[row, h*64+e] = sum_d X[row, h*64+d] * M[b,h][d][e]
__global__ __launch_bounds__(256)
void apply_k(const float* __restrict__ X, const float* __restrict__ M,
             float* __restrict__ out) {
  const int h  = blockIdx.x & 15;
  const int rt = blockIdx.x >> 4;          // 0..63 row tiles of 64
  const int b  = rt >> 5;                  // 2048 rows per batch
  __shared__ f4 Xt[64][16];                // 16 KB
  __shared__ f4 Mh[64][16];                // 16 KB
  const int t = threadIdx.x;

  const f4* xs = (const f4*)(X + (size_t)rt*64*DM_ + h*HD_);
  #pragma unroll
  for (int k = 0; k < 4; ++k) {
    int idx = t + k*256;
    Xt[idx>>4][idx&15] = xs[(size_t)(idx>>4)*(DM_/4) + (idx&15)];
  }
  const f4* ms = (const f4*)(M + (size_t)(b*N_HEADS_ + h)*4096);
  #pragma unroll
  for (int k = 0; k < 4; ++k) {
    int idx = t + k*256;
    Mh[idx>>4][idx&15] = ms[idx];
  }
  __syncthreads();

  const int ti = t >> 4, tj = t & 15;      // row-tile, e-tile
  float acc[4][4] = {};
  #pragma unroll 2
  for (int d4 = 0; d4 < 16; ++d4) {
    float xv[4][4], mv[4][4];
    #pragma unroll
    for (int i = 0; i < 4; ++i) ld4(xv[i], Xt[ti*4+i][d4]);
    #pragma unroll
    for (int dd = 0; dd < 4; ++dd) ld4(mv[dd], Mh[d4*4+dd][tj]);
    #pragma unroll
    for (int i = 0; i < 4; ++i)
      #pragma unroll
      for (int dd = 0; dd < 4; ++dd)
        #pragma unroll
        for (int j = 0; j < 4; ++j)
          acc[i][j] = fmaf(xv[i][dd], mv[dd][j], acc[i][j]);
  }

  f4* o4 = (f4*)out;
  #pragma unroll
  for (int i = 0; i < 4; ++i) {
    int row = rt*64 + ti*4 + i;
    o4[(size_t)row*(DM_/4) + h*16 + tj] =
      make_float4(acc[i][0], acc[i][1], acc[i][2], acc[i][3]);
  }
}

extern "C" void kernel_launch(void* const* d_in, const int* in_sizes, int n_in,
                              void* d_out, int out_size, void* d_ws, size_t ws_size,
                              hipStream_t stream) {
  const float* ctx = (const float*)d_in[0];   // [2,2048,1024]
  const float* X   = (const float*)d_in[1];   // [2,2048,1024]
  const float* Wq  = (const float*)d_in[2];   // [16,64,64]
  const float* Wk  = (const float*)d_in[3];
  const float* Wv  = (const float*)d_in[4];
  float* out = (float*)d_out;

  float* G = (float*)d_ws;                    // [32][64][64] = 512 KB
  float* M = G + (size_t)NBH_*4096;           // [32][64][64] = 512 KB

  hipMemsetAsync(G, 0, (size_t)NBH_*4096*sizeof(float), stream);
  gram_k   <<<NBH_*NCHUNK_, 256, 0, stream>>>(ctx, G);
  combine_k<<<NBH_,          256, 0, stream>>>(Wq, Wk, Wv, G, M);
  apply_k  <<<(NB_*SEQ_/64)*N_HEADS_, 256, 0, stream>>>(X, M, out);
}

// Round 9
// 120.679 us; speedup vs baseline: 1.1580x; 1.1580x over previous
//
#include <hip/hip_runtime.h>

// MultiHeadCrossAttention without softmax => fully linear:
//   out[b,q,h,:] = Xh[b,q,h,:] @ M[b,h]
//   M[b,h] = scale * Wq[h]^T @ Wk[h] @ (Ch^T Ch) @ Wv[h]^T
// Shapes (fixed by harness): B=2, SQ=SKV=2048, H=16, d=64, D=1024, fp32.
//
// Round 9 == round 2 resubmit (7x broker timeout, never ran): no atomics.
// gram_k stores per-chunk partial Gram matrices (plain f4 stores);
// combine_k reduces the 16 partials per (b,h) in registers into LDS,
// then does the three 64^3 matmuls. 3 dispatches.

#define N_HEADS_ 16
#define HD_      64
#define NB_      2
#define SEQ_     2048
#define DM_      1024          // N_HEADS_*HD_
#define CHUNK_   128           // rows of context per gram block
#define NCHUNK_  (SEQ_/CHUNK_) // 16
#define NBH_     (NB_*N_HEADS_) // 32

typedef float4 f4;

__device__ __forceinline__ void ld4(float (&d)[4], const f4 v) {
  d[0]=v.x; d[1]=v.y; d[2]=v.z; d[3]=v.w;
}

// ---------------- Kernel 1: partial Gram  Gp[chunk,bh] = Cchunk^T Cchunk
__global__ __launch_bounds__(256)
void gram_k(const float* __restrict__ ctx, float* __restrict__ Gp) {
  const int bh    = blockIdx.x & 31;
  const int chunk = blockIdx.x >> 5;
  const int b = bh >> 4, h = bh & 15;
  __shared__ f4 cT[CHUNK_][16];            // 128 x 64 floats = 32 KB
  const int t = threadIdx.x;
  const f4* src = (const f4*)(ctx + ((size_t)(b*SEQ_ + chunk*CHUNK_))*DM_ + h*HD_);
  #pragma unroll
  for (int k = 0; k < (CHUNK_*16)/256; ++k) {   // 8
    int idx = t + k*256;
    cT[idx>>4][idx&15] = src[(size_t)(idx>>4)*(DM_/4) + (idx&15)];
  }
  __syncthreads();
  const int ti = t >> 4, tj = t & 15;
  float acc[4][4] = {};
  #pragma unroll 4
  for (int s = 0; s < CHUNK_; ++s) {
    float ev[4], fv[4];
    ld4(ev, cT[s][ti]);
    ld4(fv, cT[s][tj]);
    #pragma unroll
    for (int i = 0; i < 4; ++i)
      #pragma unroll
      for (int j = 0; j < 4; ++j)
        acc[i][j] = fmaf(ev[i], fv[j], acc[i][j]);
  }
  f4* g4 = (f4*)(Gp + (size_t)blockIdx.x*4096);
  #pragma unroll
  for (int i = 0; i < 4; ++i)
    g4[(ti*4+i)*16 + tj] = make_float4(acc[i][0], acc[i][1], acc[i][2], acc[i][3]);
}

// ---------------- Kernel 2: reduce partials + M = scale * Wq^T (Wk G Wv^T)
__device__ __forceinline__ void load_mat64(f4 (*dst)[16], const float* __restrict__ src, int t) {
  const f4* s4 = (const f4*)src;
  #pragma unroll
  for (int k = 0; k < 4; ++k) {
    int idx = t + k*256;
    dst[idx>>4][idx&15] = s4[idx];
  }
}

__global__ __launch_bounds__(256)
void combine_k(const float* __restrict__ Wq, const float* __restrict__ Wk,
               const float* __restrict__ Wv, const float* __restrict__ Gp,
               float* __restrict__ M) {
  const int bh = blockIdx.x;               // 0..31
  const int h  = bh & 15;
  __shared__ f4 bufA[64][16], bufB[64][16], bufC[64][16];   // 48 KB
  const int t = threadIdx.x;
  const int ti = t >> 4, tj = t & 15;

  load_mat64(bufA, Wk + (size_t)h*4096, t);      // A = Wk  [e][d1]

  // Reduce the 16 chunk-partials of G into bufB (registers, no atomics).
  const f4* gp4 = (const f4*)Gp;
  #pragma unroll
  for (int k = 0; k < 4; ++k) {
    int idx = t + k*256;
    float sx=0.f, sy=0.f, sz=0.f, sw=0.f;
    #pragma unroll 4
    for (int c = 0; c < NCHUNK_; ++c) {
      f4 v = gp4[(size_t)((c<<5) | bh)*1024 + idx];
      sx += v.x; sy += v.y; sz += v.z; sw += v.w;
    }
    bufB[idx>>4][idx&15] = make_float4(sx, sy, sz, sw);     // B = G [d1][d2]
  }
  __syncthreads();

  // Phase A: T1[e][d2] = sum_d1 Wk[e][d1] * G[d1][d2]  -> bufC
  {
    float acc[4][4] = {};
    #pragma unroll 2
    for (int d14 = 0; d14 < 16; ++d14) {
      float a[4][4];
      #pragma unroll
      for (int i = 0; i < 4; ++i) ld4(a[i], bufA[ti*4+i][d14]);
      #pragma unroll
      for (int dd = 0; dd < 4; ++dd) {
        float g[4]; ld4(g, bufB[d14*4+dd][tj]);
        #pragma unroll
        for (int i = 0; i < 4; ++i)
          #pragma unroll
          for (int j = 0; j < 4; ++j)
            acc[i][j] = fmaf(a[i][dd], g[j], acc[i][j]);
      }
    }
    #pragma unroll
    for (int i = 0; i < 4; ++i)
      bufC[ti*4+i][tj] = make_float4(acc[i][0], acc[i][1], acc[i][2], acc[i][3]);
  }
  __syncthreads();
  load_mat64(bufA, Wv + (size_t)h*4096, t);      // A = Wv  [f][d2]
  __syncthreads();

  // Phase B: T2[e][f] = sum_d2 T1[e][d2] * Wv[f][d2]  -> bufB
  {
    float acc[4][4] = {};
    #pragma unroll 2
    for (int d4 = 0; d4 < 16; ++d4) {
      float a[4][4], w[4][4];
      #pragma unroll
      for (int i = 0; i < 4; ++i) ld4(a[i], bufC[ti*4+i][d4]);
      #pragma unroll
      for (int j = 0; j < 4; ++j) ld4(w[j], bufA[tj*4+j][d4]);
      #pragma unroll
      for (int i = 0; i < 4; ++i)
        #pragma unroll
        for (int j = 0; j < 4; ++j) {
          #pragma unroll
          for (int dd = 0; dd < 4; ++dd)
            acc[i][j] = fmaf(a[i][dd], w[j][dd], acc[i][j]);
        }
    }
    __syncthreads();   // all reads of bufB (G) done before overwrite
    #pragma unroll
    for (int i = 0; i < 4; ++i)
      bufB[ti*4+i][tj] = make_float4(acc[i][0], acc[i][1], acc[i][2], acc[i][3]);
  }
  __syncthreads();
  load_mat64(bufC, Wq + (size_t)h*4096, t);      // C = Wq  [f][d]
  __syncthreads();

  // Phase C: M[d][e'] = scale * sum_f Wq[f][d] * T2[f][e']
  {
    float acc[4][4] = {};
    #pragma unroll 4
    for (int f = 0; f < 64; ++f) {
      float wq[4], t2[4];
      ld4(wq, bufC[f][ti]);
      ld4(t2, bufB[f][tj]);
      #pragma unroll
      for (int i = 0; i < 4; ++i)
        #pragma unroll
        for (int j = 0; j < 4; ++j)
          acc[i][j] = fmaf(wq[i], t2[j], acc[i][j]);
    }
    const float scale = 0.125f;   // 64^-0.5
    f4* m4 = (f4*)(M + (size_t)bh*4096);
    #pragma unroll
    for (int i = 0; i < 4; ++i)
      m4[(ti*4+i)*16 + tj] = make_float4(scale*acc[i][0], scale*acc[i][1],
                                         scale*acc[i][2], scale*acc[i][3]);
  }
}

// ---------------- Kernel 3: out[row, h*64+e] = sum_d X[row, h*64+d] * M[b,h][d][e]
__global__ __launch_bounds__(256)
void apply_k(const float* __restrict__ X, const float* __restrict__ M,
             float* __restrict__ out) {
  const int h  = blockIdx.x & 15;
  const int rt = blockIdx.x >> 4;          // 0..63 row tiles of 64
  const int b  = rt >> 5;                  // 2048 rows per batch
  __shared__ f4 Xt[64][16];                // 16 KB
  __shared__ f4 Mh[64][16];                // 16 KB
  const int t = threadIdx.x;

  const f4* xs = (const f4*)(X + (size_t)rt*64*DM_ + h*HD_);
  #pragma unroll
  for (int k = 0; k < 4; ++k) {
    int idx = t + k*256;
    Xt[idx>>4][idx&15] = xs[(size_t)(idx>>4)*(DM_/4) + (idx&15)];
  }
  const f4* ms = (const f4*)(M + (size_t)(b*N_HEADS_ + h)*4096);
  #pragma unroll
  for (int k = 0; k < 4; ++k) {
    int idx = t + k*256;
    Mh[idx>>4][idx&15] = ms[idx];
  }
  __syncthreads();

  const int ti = t >> 4, tj = t & 15;      // row-tile, e-tile
  float acc[4][4] = {};
  #pragma unroll 2
  for (int d4 = 0; d4 < 16; ++d4) {
    float xv[4][4], mv[4][4];
    #pragma unroll
    for (int i = 0; i < 4; ++i) ld4(xv[i], Xt[ti*4+i][d4]);
    #pragma unroll
    for (int dd = 0; dd < 4; ++dd) ld4(mv[dd], Mh[d4*4+dd][tj]);
    #pragma unroll
    for (int i = 0; i < 4; ++i)
      #pragma unroll
      for (int dd = 0; dd < 4; ++dd)
        #pragma unroll
        for (int j = 0; j < 4; ++j)
          acc[i][j] = fmaf(xv[i][dd], mv[dd][j], acc[i][j]);
  }

  f4* o4 = (f4*)out;
  #pragma unroll
  for (int i = 0; i < 4; ++i) {
    int row = rt*64 + ti*4 + i;
    o4[(size_t)row*(DM_/4) + h*16 + tj] =
      make_float4(acc[i][0], acc[i][1], acc[i][2], acc[i][3]);
  }
}

extern "C" void kernel_launch(void* const* d_in, const int* in_sizes, int n_in,
                              void* d_out, int out_size, void* d_ws, size_t ws_size,
                              hipStream_t stream) {
  const float* ctx = (const float*)d_in[0];   // [2,2048,1024]
  const float* X   = (const float*)d_in[1];   // [2,2048,1024]
  const float* Wq  = (const float*)d_in[2];   // [16,64,64]
  const float* Wk  = (const float*)d_in[3];
  const float* Wv  = (const float*)d_in[4];
  float* out = (float*)d_out;

  float* Gp = (float*)d_ws;                      // [512][64][64] = 8 MB partials
  float* M  = Gp + (size_t)NBH_*NCHUNK_*4096;    // [32][64][64]  = 512 KB

  gram_k   <<<NBH_*NCHUNK_, 256, 0, stream>>>(ctx, Gp);
  combine_k<<<NBH_,          256, 0, stream>>>(Wq, Wk, Wv, Gp, M);
  apply_k  <<<(NB_*SEQ_/64)*N_HEADS_, 256, 0, stream>>>(X, M, out);
}

// Round 11
// 119.335 us; speedup vs baseline: 1.1711x; 1.0113x over previous
//
#include <hip/hip_runtime.h>

// MultiHeadCrossAttention without softmax => fully linear:
//   out[b,q,h,:] = Xh[b,q,h,:] @ M[b,h]
//   M[b,h] = scale * Wq[h]^T @ Wk[h] @ (Ch^T Ch) @ Wv[h]^T
// Shapes (fixed by harness): B=2, SQ=SKV=2048, H=16, d=64, D=1024, fp32.
//
// Round 11 == round 10 resubmit (broker timeout, never ran).
// Sensitivity probe: gram_k does 2 chunks per block (256 blocks),
// halving Gp partial traffic 8 MB -> 4 MB (write+read). If dur_us is
// insensitive (~120), the timed window is dominated by harness poison
// fills (43.5 us x 256 MiB each) and our ~14 us of kernels are at the
// decomposition floor -> ROOFLINE next round.

#define N_HEADS_ 16
#define HD_      64
#define NB_      2
#define SEQ_     2048
#define DM_      1024            // N_HEADS_*HD_
#define CHUNK_   128             // rows of context staged per LDS refill
#define CPB_     2               // chunks per gram block
#define NGBLK_   (SEQ_/(CHUNK_*CPB_))  // 8 gram blocks per bh
#define NBH_     (NB_*N_HEADS_)  // 32

typedef float4 f4;

__device__ __forceinline__ void ld4(float (&d)[4], const f4 v) {
  d[0]=v.x; d[1]=v.y; d[2]=v.z; d[3]=v.w;
}

// ---------------- Kernel 1: partial Gram over 2 chunks -----------------
// Gp[gblk,bh] = sum over 256 rows of ctx slice (2 x 128-row LDS passes)
__global__ __launch_bounds__(256)
void gram_k(const float* __restrict__ ctx, float* __restrict__ Gp) {
  const int bh = blockIdx.x & 31;
  const int gb = blockIdx.x >> 5;          // 0..7
  const int b = bh >> 4, h = bh & 15;
  __shared__ f4 cT[CHUNK_][16];            // 128 x 64 floats = 32 KB
  const int t = threadIdx.x;
  const int ti = t >> 4, tj = t & 15;
  float acc[4][4] = {};

  #pragma unroll
  for (int cc = 0; cc < CPB_; ++cc) {
    const int chunk = gb*CPB_ + cc;
    const f4* src = (const f4*)(ctx + ((size_t)(b*SEQ_ + chunk*CHUNK_))*DM_ + h*HD_);
    #pragma unroll
    for (int k = 0; k < (CHUNK_*16)/256; ++k) {   // 8
      int idx = t + k*256;
      cT[idx>>4][idx&15] = src[(size_t)(idx>>4)*(DM_/4) + (idx&15)];
    }
    __syncthreads();
    #pragma unroll 4
    for (int s = 0; s < CHUNK_; ++s) {
      float ev[4], fv[4];
      ld4(ev, cT[s][ti]);
      ld4(fv, cT[s][tj]);
      #pragma unroll
      for (int i = 0; i < 4; ++i)
        #pragma unroll
        for (int j = 0; j < 4; ++j)
          acc[i][j] = fmaf(ev[i], fv[j], acc[i][j]);
    }
    __syncthreads();   // all reads done before next refill
  }

  f4* g4 = (f4*)(Gp + (size_t)blockIdx.x*4096);
  #pragma unroll
  for (int i = 0; i < 4; ++i)
    g4[(ti*4+i)*16 + tj] = make_float4(acc[i][0], acc[i][1], acc[i][2], acc[i][3]);
}

// ---------------- Kernel 2: reduce partials + M = scale * Wq^T (Wk G Wv^T)
__device__ __forceinline__ void load_mat64(f4 (*dst)[16], const float* __restrict__ src, int t) {
  const f4* s4 = (const f4*)src;
  #pragma unroll
  for (int k = 0; k < 4; ++k) {
    int idx = t + k*256;
    dst[idx>>4][idx&15] = s4[idx];
  }
}

__global__ __launch_bounds__(256)
void combine_k(const float* __restrict__ Wq, const float* __restrict__ Wk,
               const float* __restrict__ Wv, const float* __restrict__ Gp,
               float* __restrict__ M) {
  const int bh = blockIdx.x;               // 0..31
  const int h  = bh & 15;
  __shared__ f4 bufA[64][16], bufB[64][16], bufC[64][16];   // 48 KB
  const int t = threadIdx.x;
  const int ti = t >> 4, tj = t & 15;

  load_mat64(bufA, Wk + (size_t)h*4096, t);      // A = Wk  [e][d1]

  // Reduce the 8 gram-block partials of G into bufB (registers, no atomics).
  const f4* gp4 = (const f4*)Gp;
  #pragma unroll
  for (int k = 0; k < 4; ++k) {
    int idx = t + k*256;
    float sx=0.f, sy=0.f, sz=0.f, sw=0.f;
    #pragma unroll 4
    for (int c = 0; c < NGBLK_; ++c) {
      f4 v = gp4[(size_t)((c<<5) | bh)*1024 + idx];
      sx += v.x; sy += v.y; sz += v.z; sw += v.w;
    }
    bufB[idx>>4][idx&15] = make_float4(sx, sy, sz, sw);     // B = G [d1][d2]
  }
  __syncthreads();

  // Phase A: T1[e][d2] = sum_d1 Wk[e][d1] * G[d1][d2]  -> bufC
  {
    float acc[4][4] = {};
    #pragma unroll 2
    for (int d14 = 0; d14 < 16; ++d14) {
      float a[4][4];
      #pragma unroll
      for (int i = 0; i < 4; ++i) ld4(a[i], bufA[ti*4+i][d14]);
      #pragma unroll
      for (int dd = 0; dd < 4; ++dd) {
        float g[4]; ld4(g, bufB[d14*4+dd][tj]);
        #pragma unroll
        for (int i = 0; i < 4; ++i)
          #pragma unroll
          for (int j = 0; j < 4; ++j)
            acc[i][j] = fmaf(a[i][dd], g[j], acc[i][j]);
      }
    }
    #pragma unroll
    for (int i = 0; i < 4; ++i)
      bufC[ti*4+i][tj] = make_float4(acc[i][0], acc[i][1], acc[i][2], acc[i][3]);
  }
  __syncthreads();
  load_mat64(bufA, Wv + (size_t)h*4096, t);      // A = Wv  [f][d2]
  __syncthreads();

  // Phase B: T2[e][f] = sum_d2 T1[e][d2] * Wv[f][d2]  -> bufB
  {
    float acc[4][4] = {};
    #pragma unroll 2
    for (int d4 = 0; d4 < 16; ++d4) {
      float a[4][4], w[4][4];
      #pragma unroll
      for (int i = 0; i < 4; ++i) ld4(a[i], bufC[ti*4+i][d4]);
      #pragma unroll
      for (int j = 0; j < 4; ++j) ld4(w[j], bufA[tj*4+j][d4]);
      #pragma unroll
      for (int i = 0; i < 4; ++i)
        #pragma unroll
        for (int j = 0; j < 4; ++j) {
          #pragma unroll
          for (int dd = 0; dd < 4; ++dd)
            acc[i][j] = fmaf(a[i][dd], w[j][dd], acc[i][j]);
        }
    }
    __syncthreads();   // all reads of bufB (G) done before overwrite
    #pragma unroll
    for (int i = 0; i < 4; ++i)
      bufB[ti*4+i][tj] = make_float4(acc[i][0], acc[i][1], acc[i][2], acc[i][3]);
  }
  __syncthreads();
  load_mat64(bufC, Wq + (size_t)h*4096, t);      // C = Wq  [f][d]
  __syncthreads();

  // Phase C: M[d][e'] = scale * sum_f Wq[f][d] * T2[f][e']
  {
    float acc[4][4] = {};
    #pragma unroll 4
    for (int f = 0; f < 64; ++f) {
      float wq[4], t2[4];
      ld4(wq, bufC[f][ti]);
      ld4(t2, bufB[f][tj]);
      #pragma unroll
      for (int i = 0; i < 4; ++i)
        #pragma unroll
        for (int j = 0; j < 4; ++j)
          acc[i][j] = fmaf(wq[i], t2[j], acc[i][j]);
    }
    const float scale = 0.125f;   // 64^-0.5
    f4* m4 = (f4*)(M + (size_t)bh*4096);
    #pragma unroll
    for (int i = 0; i < 4; ++i)
      m4[(ti*4+i)*16 + tj] = make_float4(scale*acc[i][0], scale*acc[i][1],
                                         scale*acc[i][2], scale*acc[i][3]);
  }
}

// ---------------- Kernel 3: out[row, h*64+e] = sum_d X[row, h*64+d] * M[b,h][d][e]
__global__ __launch_bounds__(256)
void apply_k(const float* __restrict__ X, const float* __restrict__ M,
             float* __restrict__ out) {
  const int h  = blockIdx.x & 15;
  const int rt = blockIdx.x >> 4;          // 0..63 row tiles of 64
  const int b  = rt >> 5;                  // 2048 rows per batch
  __shared__ f4 Xt[64][16];                // 16 KB
  __shared__ f4 Mh[64][16];                // 16 KB
  const int t = threadIdx.x;

  const f4* xs = (const f4*)(X + (size_t)rt*64*DM_ + h*HD_);
  #pragma unroll
  for (int k = 0; k < 4; ++k) {
    int idx = t + k*256;
    Xt[idx>>4][idx&15] = xs[(size_t)(idx>>4)*(DM_/4) + (idx&15)];
  }
  const f4* ms = (const f4*)(M + (size_t)(b*N_HEADS_ + h)*4096);
  #pragma unroll
  for (int k = 0; k < 4; ++k) {
    int idx = t + k*256;
    Mh[idx>>4][idx&15] = ms[idx];
  }
  __syncthreads();

  const int ti = t >> 4, tj = t & 15;      // row-tile, e-tile
  float acc[4][4] = {};
  #pragma unroll 2
  for (int d4 = 0; d4 < 16; ++d4) {
    float xv[4][4], mv[4][4];
    #pragma unroll
    for (int i = 0; i < 4; ++i) ld4(xv[i], Xt[ti*4+i][d4]);
    #pragma unroll
    for (int dd = 0; dd < 4; ++dd) ld4(mv[dd], Mh[d4*4+dd][tj]);
    #pragma unroll
    for (int i = 0; i < 4; ++i)
      #pragma unroll
      for (int dd = 0; dd < 4; ++dd)
        #pragma unroll
        for (int j = 0; j < 4; ++j)
          acc[i][j] = fmaf(xv[i][dd], mv[dd][j], acc[i][j]);
  }

  f4* o4 = (f4*)out;
  #pragma unroll
  for (int i = 0; i < 4; ++i) {
    int row = rt*64 + ti*4 + i;
    o4[(size_t)row*(DM_/4) + h*16 + tj] =
      make_float4(acc[i][0], acc[i][1], acc[i][2], acc[i][3]);
  }
}

extern "C" void kernel_launch(void* const* d_in, const int* in_sizes, int n_in,
                              void* d_out, int out_size, void* d_ws, size_t ws_size,
                              hipStream_t stream) {
  const float* ctx = (const float*)d_in[0];   // [2,2048,1024]
  const float* X   = (const float*)d_in[1];   // [2,2048,1024]
  const float* Wq  = (const float*)d_in[2];   // [16,64,64]
  const float* Wk  = (const float*)d_in[3];
  const float* Wv  = (const float*)d_in[4];
  float* out = (float*)d_out;

  float* Gp = (float*)d_ws;                      // [256][64][64] = 4 MB partials
  float* M  = Gp + (size_t)NBH_*NGBLK_*4096;     // [32][64][64]  = 512 KB

  gram_k   <<<NBH_*NGBLK_, 256, 0, stream>>>(ctx, Gp);
  combine_k<<<NBH_,         256, 0, stream>>>(Wq, Wk, Wv, Gp, M);
  apply_k  <<<(NB_*SEQ_/64)*N_HEADS_, 256, 0, stream>>>(X, M, out);
}